// Round 6
// baseline (419.046 us; speedup 1.0000x reference)
//
#include <hip/hip_runtime.h>

#define N_NODES 102

typedef _Float16 f16x8 __attribute__((ext_vector_type(8)));
typedef _Float16 f16x2 __attribute__((ext_vector_type(2)));
typedef float f32x4 __attribute__((ext_vector_type(4)));

#define GLOAD_LDS16(src, dst) \
    __builtin_amdgcn_global_load_lds((const __attribute__((address_space(1))) void*)(src), \
                                     (__attribute__((address_space(3))) void*)(dst), 16, 0, 0)

// ---------------- Kernel 1: build normalized adjacency (exactly per reference) ---
__global__ void build_adj(const int* __restrict__ ei, int ne, float* __restrict__ A) {
    __shared__ int deg[N_NODES];
    __shared__ float dinv[N_NODES];
    int t = threadIdx.x;
    if (t < N_NODES) deg[t] = 1;  // self-loop
    __syncthreads();
    if (t == 0) {
        for (int e = 0; e < ne; ++e) deg[ei[ne + e]] += 1;  // deg over col index
    }
    __syncthreads();
    if (t < N_NODES) dinv[t] = 1.0f / sqrtf((float)deg[t]);
    __syncthreads();
    for (int i = t; i < N_NODES * N_NODES; i += blockDim.x) A[i] = 0.0f;
    __syncthreads();
    if (t == 0) {
        for (int e = 0; e < ne; ++e) {
            int r = ei[e], c = ei[ne + e];
            A[c * N_NODES + r] += dinv[r] * dinv[c];   // out[col] += norm * x[row]
        }
    }
    __syncthreads();
    if (t < N_NODES) A[t * N_NODES + t] += dinv[t] * dinv[t];  // diagonal self-loops
}

// ---------------- Kernel 1b: prep weights: WpT f16, transposed + pre-swizzled ----
// WpT layout per col-block cb: f16 idx = cc*256 + (k ^ ((cc&7)<<3)), value Wp[k][cb*64+cc]
// so a LINEAR global_load_lds produces an LDS image whose read-side XOR is the same.
__global__ void prep_w(const float* __restrict__ Wp, const float* __restrict__ Wg,
                       const float* __restrict__ bg,
                       _Float16* __restrict__ WpT, _Float16* __restrict__ Wg16,
                       _Float16* __restrict__ bg16) {
    int tid = blockIdx.x * 256 + threadIdx.x;          // grid 64 x 256 = 16384
    for (int i = tid; i < 65536; i += 16384) {         // i = k*256 + col (coalesced load)
        int col = i & 255, k = i >> 8;
        int cb = col >> 6, cc = col & 63;
        _Float16 v = (_Float16)Wp[i];
        WpT[(cb << 14) + (cc << 8) + (k ^ ((cc & 7) << 3))] = v;
    }
    if (tid < 512) Wg16[tid] = (_Float16)Wg[tid];
    if (tid < 256) bg16[tid] = (_Float16)bg[tid];
}

// ---------------- Kernel 2: y[p][v][c] = sum_u A[v,u] * xf[p,u,c] ----------------
__global__ void compute_y(const float* __restrict__ x,
                          const float* __restrict__ A,
                          float* __restrict__ y) {
    int p = blockIdx.x;
    __shared__ float xs[N_NODES * 2];
    int t = threadIdx.x;
    const float* xp = x + (size_t)p * (N_NODES * 2);
    for (int i = t; i < N_NODES * 2; i += 128) xs[i] = xp[i];
    __syncthreads();
    if (t < N_NODES) {
        float a0 = 0.0f, a1 = 0.0f;
        const float* Arow = A + t * N_NODES;
        for (int u = 0; u < N_NODES; ++u) {
            float a = Arow[u];
            a0 += a * xs[2 * u];
            a1 += a * xs[2 * u + 1];
        }
        size_t r = (size_t)p * N_NODES + t;
        y[r * 2]     = a0;
        y[r * 2 + 1] = a1;
    }
}

// ---------------- Kernel 3: out[r][e] = relu(y0*W0 + y1*W1 + b) @ Wp + bp --------
// Swapped-operand MFMA: A = W_proj tile (LDS, global_load_lds staged, XOR-swizzled),
// B = h generated in-register from y. 1024 rows/block (4 phases x 256 rows), 64 cols.
// Nontemporal float4 stores (write-once output; avoid L2 write-allocate RMW).
__global__ __launch_bounds__(256, 2) void gnn_main(
    const float* __restrict__ y,        // [R][2] fp32
    const _Float16* __restrict__ WpT,   // [4][64][256] f16, pre-swizzled
    const _Float16* __restrict__ Wg16,  // [2][256] f16
    const _Float16* __restrict__ bg16,  // [256] f16
    const float* __restrict__ bp,       // [256]
    float* __restrict__ out)            // [R][256]
{
    __shared__ _Float16 Wl[64 * 256];   // 32 KB, swizzled image
    __shared__ _Float16 W0l[256], W1l[256], bgl[256];
    const int tid = threadIdx.x;
    const int cb  = blockIdx.y;
    const int c0  = cb * 64;

    const int w  = tid >> 6;   // wave 0..3
    const int l  = tid & 63;   // lane
    const int qk = l >> 4;     // lane quad 0..3
    const int m  = l & 15;
    const int xr = (m & 7) << 3;

    // Stage W_proj slice: 8 x global_load_lds (16B/lane), linear dest, pre-swizzled src
    {
        const f16x8* src = reinterpret_cast<const f16x8*>(WpT) + (cb << 11) + (w << 9) + l;
        _Float16* dstb = &Wl[(w << 12)];
        #pragma unroll
        for (int j = 0; j < 8; ++j)
            GLOAD_LDS16(src + (j << 6), dstb + (j << 9));
    }
    // Stage GNN weights (f16, tiny)
    W0l[tid] = Wg16[tid];
    W1l[tid] = Wg16[256 + tid];
    bgl[tid] = bg16[tid];
    __syncthreads();

    // b_proj slice for this lane's 4 consecutive output cols per fragment
    f32x4 bp4[4];
    #pragma unroll
    for (int nt = 0; nt < 4; ++nt)
        bp4[nt] = *reinterpret_cast<const f32x4*>(&bp[c0 + nt * 16 + qk * 4]);

    const f16x2 z2 = (f16x2){ (_Float16)0.0f, (_Float16)0.0f };

    for (int ph = 0; ph < 4; ++ph) {
        const long rowbase = (long)blockIdx.x * 1024 + ph * 256 + (long)w * 64;

        // y for this lane's B-frag rows
        f16x2 y0pk[4], y1pk[4];
        #pragma unroll
        for (int s = 0; s < 4; ++s) {
            long r = rowbase + s * 16 + m;
            float2 yv = *reinterpret_cast<const float2*>(&y[r * 2]);
            _Float16 h0 = (_Float16)yv.x;
            _Float16 h1 = (_Float16)yv.y;
            y0pk[s] = (f16x2){ h0, h0 };
            y1pk[s] = (f16x2){ h1, h1 };
        }

        f32x4 acc[4][4];
        #pragma unroll
        for (int s = 0; s < 4; ++s)
            #pragma unroll
            for (int nt = 0; nt < 4; ++nt)
                acc[s][nt] = (f32x4){0.f, 0.f, 0.f, 0.f};

        #pragma unroll
        for (int t = 0; t < 8; ++t) {
            const int kk = 32 * t + (qk << 3);      // unswizzled k (small arrays)
            const int k2 = kk ^ xr;                 // swizzled k (Wl)
            union { f16x8 v; f16x2 p[4]; } w0u, w1u, bbu;
            w0u.v = *reinterpret_cast<const f16x8*>(&W0l[kk]);
            w1u.v = *reinterpret_cast<const f16x8*>(&W1l[kk]);
            bbu.v = *reinterpret_cast<const f16x8*>(&bgl[kk]);
            f16x8 afrag[4];
            #pragma unroll
            for (int nt = 0; nt < 4; ++nt)
                afrag[nt] = *reinterpret_cast<const f16x8*>(&Wl[((nt * 16 + m) << 8) + k2]);
            #pragma unroll
            for (int s = 0; s < 4; ++s) {
                union { f16x8 v; f16x2 p[4]; } bf;
                #pragma unroll
                for (int j2 = 0; j2 < 4; ++j2) {
                    f16x2 h = w0u.p[j2] * y0pk[s] + w1u.p[j2] * y1pk[s] + bbu.p[j2];
                    bf.p[j2] = __builtin_elementwise_max(h, z2);
                }
                #pragma unroll
                for (int nt = 0; nt < 4; ++nt)
                    acc[s][nt] = __builtin_amdgcn_mfma_f32_16x16x32_f16(afrag[nt], bf.v, acc[s][nt], 0, 0, 0);
            }
        }

        // Epilogue: + b_proj, nontemporal float4 stores
        #pragma unroll
        for (int s = 0; s < 4; ++s) {
            float* rowp = out + (rowbase + s * 16 + m) * 256 + c0 + (qk << 2);
            #pragma unroll
            for (int nt = 0; nt < 4; ++nt) {
                f32x4 v = acc[s][nt] + bp4[nt];
                __builtin_nontemporal_store(v, reinterpret_cast<f32x4*>(rowp + nt * 16));
            }
        }
    }
}

extern "C" void kernel_launch(void* const* d_in, const int* in_sizes, int n_in,
                              void* d_out, int out_size, void* d_ws, size_t ws_size,
                              hipStream_t stream) {
    const float* x  = (const float*)d_in[0];
    const float* Wg = (const float*)d_in[1];
    const float* bg = (const float*)d_in[2];
    const float* Wp = (const float*)d_in[3];
    const float* bp = (const float*)d_in[4];
    const int* ei   = (const int*)d_in[5];
    float* out = (float*)d_out;

    const int ne    = in_sizes[5] / 2;              // 84
    const int pairs = in_sizes[0] / (N_NODES * 2);  // 8192
    const int rows  = pairs * N_NODES;              // 835584

    char* wsb = (char*)d_ws;
    float*     yws  = (float*)wsb;                                   // rows*2 f32
    float*     A    = (float*)(wsb + (size_t)rows * 2 * sizeof(float));
    _Float16*  WpT  = (_Float16*)(wsb + (size_t)rows * 2 * sizeof(float) + 10404 * sizeof(float));
    _Float16*  Wg16 = WpT + 65536;
    _Float16*  bg16 = Wg16 + 512;

    build_adj<<<1, 128, 0, stream>>>(ei, ne, A);
    prep_w<<<64, 256, 0, stream>>>(Wp, Wg, bg, WpT, Wg16, bg16);
    compute_y<<<pairs, 128, 0, stream>>>(x, A, yws);

    const int rowblocks = rows / 1024;              // 816
    gnn_main<<<dim3(rowblocks, 4), 256, 0, stream>>>(yws, WpT, Wg16, bg16, bp, out);
}

// Round 7
// 323.316 us; speedup vs baseline: 1.2961x; 1.2961x over previous
//
#include <hip/hip_runtime.h>

#define N_NODES 102

typedef _Float16 f16x8 __attribute__((ext_vector_type(8)));
typedef _Float16 f16x2 __attribute__((ext_vector_type(2)));
typedef float f32x4 __attribute__((ext_vector_type(4)));

#define LDW 264  // padded LDS row stride in f16 elems (264*2B = 528B, odd 16B units)

// ---------------- Kernel 1: build normalized adjacency (exactly per reference) ---
__global__ void build_adj(const int* __restrict__ ei, int ne, float* __restrict__ A) {
    __shared__ int deg[N_NODES];
    __shared__ float dinv[N_NODES];
    int t = threadIdx.x;
    if (t < N_NODES) deg[t] = 1;  // self-loop
    __syncthreads();
    if (t == 0) {
        for (int e = 0; e < ne; ++e) deg[ei[ne + e]] += 1;  // deg over col index
    }
    __syncthreads();
    if (t < N_NODES) dinv[t] = 1.0f / sqrtf((float)deg[t]);
    __syncthreads();
    for (int i = t; i < N_NODES * N_NODES; i += blockDim.x) A[i] = 0.0f;
    __syncthreads();
    if (t == 0) {
        for (int e = 0; e < ne; ++e) {
            int r = ei[e], c = ei[ne + e];
            A[c * N_NODES + r] += dinv[r] * dinv[c];   // out[col] += norm * x[row]
        }
    }
    __syncthreads();
    if (t < N_NODES) A[t * N_NODES + t] += dinv[t] * dinv[t];  // diagonal self-loops
}

// ---------------- Kernel 2: y[p][v][c] = sum_u A[v,u] * xf[p,u,c] ----------------
// A staged in LDS with row stride 103 (odd): lane v reads As[v*103+u] ->
// banks (7v+u)%32, 2 lanes/bank = conflict-free. Global A reads fully coalesced.
__global__ __launch_bounds__(128) void compute_y(const float* __restrict__ x,
                                                 const float* __restrict__ A,
                                                 float* __restrict__ y) {
    __shared__ float As[N_NODES * 103];   // 42.0 KB
    __shared__ float xs[N_NODES * 2];
    int p = blockIdx.x;
    int t = threadIdx.x;
    // Stage A coalesced (i = v*102 + u)
    for (int i = t; i < N_NODES * N_NODES; i += 128) {
        int v = i / N_NODES;
        int u = i - v * N_NODES;
        As[v * 103 + u] = A[i];
    }
    const float* xp = x + (size_t)p * (N_NODES * 2);
    for (int i = t; i < N_NODES * 2; i += 128) xs[i] = xp[i];
    __syncthreads();
    if (t < N_NODES) {
        float a0 = 0.0f, a1 = 0.0f;
        const float* Arow = &As[t * 103];
        #pragma unroll 6
        for (int u = 0; u < N_NODES; ++u) {
            float a = Arow[u];
            a0 += a * xs[2 * u];
            a1 += a * xs[2 * u + 1];
        }
        size_t r = (size_t)p * N_NODES + t;
        y[r * 2]     = a0;
        y[r * 2 + 1] = a1;
    }
}

// ---------------- Kernel 3: out[r][e] = relu(y0*W0 + y1*W1 + b) @ Wp + bp --------
// R3-verbatim: A-operand = h (in-register), B = W_proj slice (LDS). 256 thr = 4
// waves; tile 256 rows x 64 cols; weights in VGPRs; launch_bounds(256,2).
__global__ __launch_bounds__(256, 2) void gnn_main(
    const float* __restrict__ y,     // [R][2] fp32
    const float* __restrict__ Wg,    // [2][256]
    const float* __restrict__ bg,    // [256]
    const float* __restrict__ Wp,    // [256][256] (k-major)
    const float* __restrict__ bp,    // [256]
    float* __restrict__ out)         // [R][256]
{
    __shared__ _Float16 Wl[64 * LDW];
    const int tid = threadIdx.x;
    const int c0 = blockIdx.y * 64;

    // Stage W_proj[:, c0:c0+64] transposed -> Wl[cc][k] as f16
    {
        int cc = tid & 63;
        int ks = tid >> 6;
        for (int k = ks; k < 256; k += 4) {
            Wl[cc * LDW + k] = (_Float16)Wp[k * 256 + c0 + cc];
        }
    }
    __syncthreads();

    const int w  = tid >> 6;   // wave 0..3
    const int l  = tid & 63;   // lane
    const int qk = l >> 4;     // k-quarter 0..3
    const int m  = l & 15;

    // Per-lane slices of W0/W1/b as packed f16x2: k = qk*8 + 32*t + 2*j2 + {0,1}
    f16x2 w0pk[8][4], w1pk[8][4], bpk[8][4];
    #pragma unroll
    for (int t = 0; t < 8; ++t) {
        int k0 = qk * 8 + 32 * t;
        #pragma unroll
        for (int j2 = 0; j2 < 4; ++j2) {
            w0pk[t][j2] = (f16x2){ (_Float16)Wg[k0 + 2 * j2],
                                   (_Float16)Wg[k0 + 2 * j2 + 1] };
            w1pk[t][j2] = (f16x2){ (_Float16)Wg[256 + k0 + 2 * j2],
                                   (_Float16)Wg[256 + k0 + 2 * j2 + 1] };
            bpk[t][j2]  = (f16x2){ (_Float16)bg[k0 + 2 * j2],
                                   (_Float16)bg[k0 + 2 * j2 + 1] };
        }
    }

    const long rowbase = (long)blockIdx.x * 256 + (long)w * 64;

    // y per row-stripe (A-frag row = lane&15)
    f16x2 y0pk[4], y1pk[4];
    #pragma unroll
    for (int s = 0; s < 4; ++s) {
        long r = rowbase + s * 16 + m;
        float2 yv = *reinterpret_cast<const float2*>(&y[r * 2]);
        _Float16 h0 = (_Float16)yv.x;
        _Float16 h1 = (_Float16)yv.y;
        y0pk[s] = (f16x2){ h0, h0 };
        y1pk[s] = (f16x2){ h1, h1 };
    }

    f32x4 acc[4][4];
    #pragma unroll
    for (int s = 0; s < 4; ++s)
        #pragma unroll
        for (int nt = 0; nt < 4; ++nt)
            acc[s][nt] = (f32x4){0.f, 0.f, 0.f, 0.f};

    const f16x2 z2 = (f16x2){ (_Float16)0.0f, (_Float16)0.0f };

    #pragma unroll
    for (int t = 0; t < 8; ++t) {
        const int kk = qk * 8 + 32 * t;
        f16x8 bfrag[4];
        #pragma unroll
        for (int nt = 0; nt < 4; ++nt)
            bfrag[nt] = *reinterpret_cast<const f16x8*>(&Wl[(nt * 16 + m) * LDW + kk]);
        #pragma unroll
        for (int s = 0; s < 4; ++s) {
            union { f16x8 v; f16x2 p[4]; } af;
            #pragma unroll
            for (int j2 = 0; j2 < 4; ++j2) {
                f16x2 h = w0pk[t][j2] * y0pk[s] + w1pk[t][j2] * y1pk[s] + bpk[t][j2];
                af.p[j2] = __builtin_elementwise_max(h, z2);
            }
            #pragma unroll
            for (int nt = 0; nt < 4; ++nt)
                acc[s][nt] = __builtin_amdgcn_mfma_f32_16x16x32_f16(af.v, bfrag[nt], acc[s][nt], 0, 0, 0);
        }
    }

    // Epilogue: + b_proj, store fp32
    float bpf[4];
    #pragma unroll
    for (int nt = 0; nt < 4; ++nt) bpf[nt] = bp[c0 + nt * 16 + m];
    #pragma unroll
    for (int s = 0; s < 4; ++s) {
        #pragma unroll
        for (int nt = 0; nt < 4; ++nt) {
            const int e = c0 + nt * 16 + m;
            #pragma unroll
            for (int reg = 0; reg < 4; ++reg) {
                long r = rowbase + s * 16 + qk * 4 + reg;
                out[r * 256 + e] = acc[s][nt][reg] + bpf[nt];
            }
        }
    }
}

extern "C" void kernel_launch(void* const* d_in, const int* in_sizes, int n_in,
                              void* d_out, int out_size, void* d_ws, size_t ws_size,
                              hipStream_t stream) {
    const float* x  = (const float*)d_in[0];
    const float* Wg = (const float*)d_in[1];
    const float* bg = (const float*)d_in[2];
    const float* Wp = (const float*)d_in[3];
    const float* bp = (const float*)d_in[4];
    const int* ei   = (const int*)d_in[5];
    float* out = (float*)d_out;

    const int ne    = in_sizes[5] / 2;              // 84
    const int pairs = in_sizes[0] / (N_NODES * 2);  // 8192

    float* yws = (float*)d_ws;
    float* A   = (float*)((char*)d_ws + (size_t)pairs * N_NODES * 2 * sizeof(float));

    build_adj<<<1, 128, 0, stream>>>(ei, ne, A);
    compute_y<<<pairs, 128, 0, stream>>>(x, A, yws);

    const int rowblocks = pairs * N_NODES / 256;    // 3264
    gnn_main<<<dim3(rowblocks, 4), 256, 0, stream>>>(yws, Wg, bg, Wp, bp, out);
}